// Round 9
// baseline (873.607 us; speedup 1.0000x reference)
//
#include <hip/hip_runtime.h>
#include <hip/hip_fp16.h>
#include <cstdint>

typedef _Float16 f16;
typedef _Float16 f16x4 __attribute__((ext_vector_type(4)));
typedef _Float16 f16x8 __attribute__((ext_vector_type(8)));
typedef float f32x4 __attribute__((ext_vector_type(4)));

#define MFMA16(a, b, c) __builtin_amdgcn_mfma_f32_16x16x32_f16(a, b, c, 0, 0, 0)

constexpr int Lq = 1024, Nb = 8, Cc = 1024, Hh = 16, Dd = 64;
constexpr int Mrows = Lq * Nb;            // 8192
constexpr float LOG100 = 4.6051701859880913680f;
constexpr float LOG2E = 1.4426950408889634f;

// ---------- async global->LDS, 16B per lane ----------
typedef const __attribute__((address_space(1))) unsigned int* gu32p;
typedef __attribute__((address_space(3))) unsigned int* lu32p;
__device__ __forceinline__ void gl_lds16(const void* g, void* l) {
  __builtin_amdgcn_global_load_lds((gu32p)g, (lu32p)l, 16, 0, 0);
}

// ---------- f32 -> f16 convert, 8 elems/thread ----------
__global__ __launch_bounds__(256) void k_cvt(const float* __restrict__ in,
                                             f16* __restrict__ out, int n8) {
  int i = blockIdx.x * blockDim.x + threadIdx.x;
  if (i >= n8) return;
  const float4* p = (const float4*)in + (size_t)i * 2;
  float4 a = p[0], b = p[1];
  f16x8 o = {(f16)a.x, (f16)a.y, (f16)a.z, (f16)a.w,
             (f16)b.x, (f16)b.y, (f16)b.z, (f16)b.w};
  *((f16x8*)out + i) = o;
}

// ---------- generic fp16 GEMM: C = A @ B^T + bias ----------
// 128x128 tile, BK=64 (2 k-subtiles of 32), 4 waves (2x2).
template <typename OutT>
__global__ __launch_bounds__(256) void k_gemm(const f16* __restrict__ A,
                                              const f16* __restrict__ B,
                                              const float* __restrict__ bias,
                                              OutT* __restrict__ Co,
                                              int Np, int Kd) {
  __shared__ f16 Ash[128 * 64];
  __shared__ f16 Bsh[128 * 64];
  const int tid = threadIdx.x, lane = tid & 63, wid = tid >> 6;
  const int m0 = blockIdx.y * 128, n0 = blockIdx.x * 128;
  const int wy = wid >> 1, wx = wid & 1;
  const int rq = lane & 15, kq = lane >> 4;
  f32x4 acc[4][4] = {};
  const int nkt = Kd >> 6;
  for (int kt = 0; kt < nkt; ++kt) {
    __syncthreads();  // protect LDS reuse from previous iteration's reads
    for (int iss = 0; iss < 4; ++iss) {
      int cbase = (iss * 4 + wid) * 64;  // wave-uniform LDS dest
      int c = cbase + lane;
      int row = ((c >> 7) << 4) + (c & 15);
      int col = kt * 64 + ((c >> 6) & 1) * 32 + ((c >> 4) & 3) * 8;
      gl_lds16(A + (size_t)(m0 + row) * Kd + col, (char*)Ash + cbase * 16);
      gl_lds16(B + (size_t)(n0 + row) * Kd + col, (char*)Bsh + cbase * 16);
    }
    __syncthreads();  // drains vmcnt -> LDS tiles complete
    for (int ks = 0; ks < 2; ++ks) {
      f16x8 af[4], bf[4];
      for (int t = 0; t < 4; ++t)
        af[t] = *(const f16x8*)((const char*)Ash + ((((wy * 4 + t) * 2 + ks) * 64 + lane) * 16));
      for (int u = 0; u < 4; ++u)
        bf[u] = *(const f16x8*)((const char*)Bsh + ((((wx * 4 + u) * 2 + ks) * 64 + lane) * 16));
      for (int t = 0; t < 4; ++t)
        for (int u = 0; u < 4; ++u)
          acc[t][u] = MFMA16(af[t], bf[u], acc[t][u]);
    }
  }
  for (int t = 0; t < 4; ++t) {
    int row = m0 + wy * 64 + t * 16 + 4 * kq;
    for (int u = 0; u < 4; ++u) {
      int col = n0 + wx * 64 + u * 16 + rq;
      float bv = bias[col];
      for (int rr = 0; rr < 4; ++rr) {
        float v = acc[t][u][rr] + bv;
        Co[(size_t)(row + rr) * Np + col] = (OutT)v;
      }
    }
  }
}

// ---------- normalize q,k per head + head layout; transpose v ----------
__global__ __launch_bounds__(256) void k_norm(const f16* __restrict__ qkv,
                                              f16* __restrict__ qhat,
                                              f16* __restrict__ khat,
                                              f16* __restrict__ vTt) {
  __shared__ f16 vt[64][72];
  const int blk = blockIdx.x;
  const int b = blk >> 4, lc = blk & 15;
  const int h = b & 15, n = b >> 4;
  const int tid = threadIdx.x;
  const int g4 = tid >> 2, sub = tid & 3;
  const int lrow = lc * 64 + g4;
  const size_t srow = ((size_t)lrow * Nb + n) * 3072;
  for (int qk = 0; qk < 2; ++qk) {
    const f16* p = qkv + srow + qk * 1024 + h * 64 + sub * 16;
    f16x8 a = *(const f16x8*)p;
    f16x8 c2 = *(const f16x8*)(p + 8);
    float ss = 0.f;
    for (int e = 0; e < 8; ++e) { float x = (float)a[e]; ss += x * x; }
    for (int e = 0; e < 8; ++e) { float x = (float)c2[e]; ss += x * x; }
    ss += __shfl_xor(ss, 1);
    ss += __shfl_xor(ss, 2);
    float sc = 1.f / fmaxf(sqrtf(ss), 1e-12f);
    f16x8 oa, ob;
    for (int e = 0; e < 8; ++e) oa[e] = (f16)((float)a[e] * sc);
    for (int e = 0; e < 8; ++e) ob[e] = (f16)((float)c2[e] * sc);
    f16* dst = (qk ? khat : qhat) + ((size_t)b * Lq + lrow) * Dd + sub * 16;
    *(f16x8*)dst = oa;
    *(f16x8*)(dst + 8) = ob;
  }
  {
    const f16* p = qkv + srow + 2048 + h * 64 + sub * 16;
    f16x8 a = *(const f16x8*)p;
    f16x8 c2 = *(const f16x8*)(p + 8);
    for (int e = 0; e < 8; ++e) vt[g4][sub * 16 + e] = a[e];
    for (int e = 0; e < 8; ++e) vt[g4][sub * 16 + 8 + e] = c2[e];
  }
  __syncthreads();
  {
    const int d = g4;
    f16x8 oa, ob;
    for (int e = 0; e < 8; ++e) oa[e] = vt[sub * 16 + e][d];
    for (int e = 0; e < 8; ++e) ob[e] = vt[sub * 16 + 8 + e][d];
    f16* dst = vTt + ((size_t)b * Dd + d) * Lq + lc * 64 + sub * 16;
    *(f16x8*)dst = oa;
    *(f16x8*)(dst + 8) = ob;
  }
}

// ---------- attention pass 1: PV + row sums (swapped QK^T, LDS-staged K/V) ----
// XCD-grouped mapping: b = blk & 127 so the 16 q-chunk blocks of a head share
// an XCD L2 (blk == b mod 8). Lane (rq,kq) owns q-row rq; writes Ows and invl.
__global__ __launch_bounds__(256) void k_attn_pv(const f16* __restrict__ qhat,
                                                 const f16* __restrict__ khat,
                                                 const f16* __restrict__ vTt,
                                                 const float* __restrict__ lsc,
                                                 const float* __restrict__ hsc,
                                                 float* __restrict__ invlb,
                                                 f16* __restrict__ Ows) {
  __shared__ f16 Kst[4096];        // 64kv x 64d chunk-linear
  __shared__ f16 Vst[4096];        // 64d x 64kv chunk-linear
  __shared__ f16 Pst[4][1024];     // per-wave 16q x 64kv chunk-linear
  const int blk = blockIdx.x;
  const int b = blk & 127, qc = blk >> 7;
  const int h = b & 15, n = b >> 4;
  const int tid = threadIdx.x, lane = tid & 63, w = tid >> 6;
  const int rq = lane & 15, kq = lane >> 4;
  const int ib = qc * 64 + w * 16;
  const float ls = __expf(fminf(lsc[h], LOG100));
  const float hs = hsc[h];
  const float c1 = ls * LOG2E, c0 = -c1;  // exp(s*ls - ls) = exp2(s*c1 + c0)
  const f16* qb = qhat + ((size_t)b * Lq + ib) * Dd;
  f16x8 qf0 = *(const f16x8*)(qb + (size_t)rq * Dd + kq * 8);
  f16x8 qf1 = *(const f16x8*)(qb + (size_t)rq * Dd + 32 + kq * 8);
  const f16* kb = khat + (size_t)b * Lq * Dd;
  const f16* vb = vTt + (size_t)b * Dd * Lq;
  f16* Pw = Pst[w];

  float lsum = 0.f;
  f32x4 Oa[4] = {};
  for (int kt = 0; kt < 16; ++kt) {
    const int j0 = kt * 64;
    __syncthreads();
    for (int iss = 0; iss < 2; ++iss) {
      int cbase = (iss * 4 + w) * 64;   // wave-uniform LDS chunk base
      int c = cbase + lane;
      int rq_ = c & 15, kq_ = (c >> 4) & 3, h_ = (c >> 6) & 1, u_ = c >> 7;
      gl_lds16(kb + (size_t)(j0 + u_ * 16 + rq_) * Dd + h_ * 32 + kq_ * 8,
               (char*)Kst + cbase * 16);
      gl_lds16(vb + (size_t)(u_ * 16 + rq_) * Lq + j0 + h_ * 32 + kq_ * 8,
               (char*)Vst + cbase * 16);
    }
    __syncthreads();
    f32x4 s[4];
    for (int u = 0; u < 4; ++u) {
      f16x8 k0 = *(const f16x8*)(Kst + (u * 128 + lane) * 8);
      f16x8 k1 = *(const f16x8*)(Kst + (u * 128 + 64 + lane) * 8);
      f32x4 a = {0.f, 0.f, 0.f, 0.f};
      a = MFMA16(k0, qf0, a);
      a = MFMA16(k1, qf1, a);
      s[u] = a;
    }
    for (int u = 0; u < 4; ++u) {
      f16x4 t4;
      for (int rr = 0; rr < 4; ++rr) {
        float e = exp2f(fmaf(s[u][rr], c1, c0));  // unnormalized, in (0,1]
        lsum += e;
        t4[rr] = (f16)e;
      }
      int cw = (u >> 1) * 64 + ((2 * u + (kq >> 1)) & 3) * 16 + rq;
      *(f16x4*)(Pw + cw * 8 + (kq & 1) * 4) = t4;
    }
    f16x8 pa0 = *(const f16x8*)(Pw + (kq * 16 + rq) * 8);
    f16x8 pa1 = *(const f16x8*)(Pw + (64 + kq * 16 + rq) * 8);
    for (int t = 0; t < 4; ++t) {
      f16x8 v0 = *(const f16x8*)(Vst + (t * 128 + lane) * 8);
      f16x8 v1 = *(const f16x8*)(Vst + (t * 128 + 64 + lane) * 8);
      Oa[t] = MFMA16(pa0, v0, Oa[t]);
      Oa[t] = MFMA16(pa1, v1, Oa[t]);
    }
  }
  lsum += __shfl_xor(lsum, 16);
  lsum += __shfl_xor(lsum, 32);
  const float invl = 1.f / lsum;
  if (kq == 0) invlb[b * Lq + ib + rq] = invl;  // per-q-row 1/rowsum

  float invlO[4];
  for (int rr = 0; rr < 4; ++rr) invlO[rr] = __shfl(invl, 4 * kq + rr);
  for (int t = 0; t < 4; ++t) {
    for (int rr = 0; rr < 4; ++rr) {
      int iseq = ib + 4 * kq + rr;
      int d = t * 16 + rq;
      Ows[((size_t)iseq * Nb + n) * Cc + h * Dd + d] = (f16)(Oa[t][rr] * invlO[rr] * hs);
    }
  }
}

// ---------- attention pass 2: streaming exact-softmax store ----------
// Tiny LDS (8 KB) + low VGPR -> full occupancy; invl precomputed by pass 1.
__global__ __launch_bounds__(256) void k_attn_sm(const f16* __restrict__ qhat,
                                                 const f16* __restrict__ khat,
                                                 const float* __restrict__ invlb,
                                                 const float* __restrict__ lsc,
                                                 float* __restrict__ attn) {
  __shared__ f16 Kst[4096];
  const int blk = blockIdx.x;
  const int b = blk & 127, qc = blk >> 7;
  const int h = b & 15;
  const int tid = threadIdx.x, lane = tid & 63, w = tid >> 6;
  const int rq = lane & 15, kq = lane >> 4;
  const int ib = qc * 64 + w * 16;
  const float ls = __expf(fminf(lsc[h], LOG100));
  const float c1 = ls * LOG2E, c0 = -c1;
  const f16* qb = qhat + ((size_t)b * Lq + ib) * Dd;
  f16x8 qf0 = *(const f16x8*)(qb + (size_t)rq * Dd + kq * 8);
  f16x8 qf1 = *(const f16x8*)(qb + (size_t)rq * Dd + 32 + kq * 8);
  const f16* kb = khat + (size_t)b * Lq * Dd;
  const float invl = invlb[b * Lq + ib + rq];
  float* ab = attn + (size_t)b * Lq * Lq + (size_t)(ib + rq) * Lq;
  for (int kt = 0; kt < 16; ++kt) {
    const int j0 = kt * 64;
    __syncthreads();
    for (int iss = 0; iss < 2; ++iss) {
      int cbase = (iss * 4 + w) * 64;
      int c = cbase + lane;
      int rq_ = c & 15, kq_ = (c >> 4) & 3, h_ = (c >> 6) & 1, u_ = c >> 7;
      gl_lds16(kb + (size_t)(j0 + u_ * 16 + rq_) * Dd + h_ * 32 + kq_ * 8,
               (char*)Kst + cbase * 16);
    }
    __syncthreads();
    for (int u = 0; u < 4; ++u) {
      f16x8 k0 = *(const f16x8*)(Kst + (u * 128 + lane) * 8);
      f16x8 k1 = *(const f16x8*)(Kst + (u * 128 + 64 + lane) * 8);
      f32x4 a = {0.f, 0.f, 0.f, 0.f};
      a = MFMA16(k0, qf0, a);
      a = MFMA16(k1, qf1, a);
      f32x4 p;
      for (int rr = 0; rr < 4; ++rr)
        p[rr] = exp2f(fmaf(a[rr], c1, c0)) * invl;
      *(f32x4*)(ab + j0 + u * 16 + 4 * kq) = p;
    }
  }
}

extern "C" void kernel_launch(void* const* d_in, const int* in_sizes, int n_in,
                              void* d_out, int out_size, void* d_ws, size_t ws_size,
                              hipStream_t stream) {
  const float* x     = (const float*)d_in[0];
  const float* w_in  = (const float*)d_in[1];
  const float* b_in  = (const float*)d_in[2];
  const float* lsc   = (const float*)d_in[3];
  const float* hsc   = (const float*)d_in[4];
  const float* w_out = (const float*)d_in[5];
  const float* b_out = (const float*)d_in[6];
  float* out  = (float*)d_out;
  float* attn = out + (size_t)Mrows * Cc;  // outputs concatenated: (out, attn)

  char* ws = (char*)d_ws;
  f16* xh   = (f16*)(ws + 0);
  f16* wh   = (f16*)(ws + 16777216);
  f16* wo   = (f16*)(ws + 23068672);
  f16* qkv  = (f16*)(ws + 25165824);
  f16* qhat = (f16*)(ws + 75497472);
  f16* khat = (f16*)(ws + 92274688);
  f16* vTt  = (f16*)(ws + 109051904);
  f16* Ows  = (f16*)(ws + 125829120);
  float* invlb = (float*)xh;  // xh (16 MB) is dead after the QKV GEMM; reuse 512 KB
  if (ws_size < 142606336ull) return;

  k_cvt<<<(Mrows * Cc / 8 + 255) / 256, 256, 0, stream>>>(x, xh, Mrows * Cc / 8);
  k_cvt<<<(3072 * 1024 / 8 + 255) / 256, 256, 0, stream>>>(w_in, wh, 3072 * 1024 / 8);
  k_cvt<<<(1024 * 1024 / 8 + 255) / 256, 256, 0, stream>>>(w_out, wo, 1024 * 1024 / 8);
  k_gemm<f16><<<dim3(24, 64), 256, 0, stream>>>(xh, wh, b_in, qkv, 3072, 1024);
  k_norm<<<2048, 256, 0, stream>>>(qkv, qhat, khat, vTt);
  k_attn_pv<<<2048, 256, 0, stream>>>(qhat, khat, vTt, lsc, hsc, invlb, Ows);
  k_attn_sm<<<2048, 256, 0, stream>>>(qhat, khat, invlb, lsc, attn);
  k_gemm<float><<<dim3(8, 64), 256, 0, stream>>>(Ows, wo, b_out, out, 1024, 1024);
}